// Round 1
// baseline (1221.822 us; speedup 1.0000x reference)
//
#include <hip/hip_runtime.h>
#include <math.h>

#define N_NODES 100000
#define IN_C 128
#define HID 256
#define N_GRAPHS 64
#define BN_EPS 1e-5f

// ---------------- degree count ----------------
__global__ void k_count_deg(const int* __restrict__ dst, int* __restrict__ deg, int E) {
    int e = blockIdx.x * blockDim.x + threadIdx.x;
    if (e < E) atomicAdd(&deg[dst[e]], 1);
}

// ---------------- single-block exclusive scan -> rowptr, invdeg ----------------
__global__ __launch_bounds__(1024) void k_scan(const int* __restrict__ deg,
                                               int* __restrict__ rowptr,
                                               float* __restrict__ invdeg, int N) {
    __shared__ int part[1024];
    int t = threadIdx.x;
    int chunk = (N + 1023) / 1024;
    int lo = t * chunk;
    int hi = min(lo + chunk, N);
    int s = 0;
    for (int i = lo; i < hi; i++) s += deg[i];
    part[t] = s;
    __syncthreads();
    for (int off = 1; off < 1024; off <<= 1) {
        int v = (t >= off) ? part[t - off] : 0;
        __syncthreads();
        part[t] += v;
        __syncthreads();
    }
    int run = (t == 0) ? 0 : part[t - 1];
    for (int i = lo; i < hi; i++) {
        rowptr[i] = run;
        int d = deg[i];
        run += d;
        invdeg[i] = 1.0f / (float)max(d, 1);
    }
    if (t == 1023) rowptr[N] = part[1023];
}

// ---------------- fill CSR + per-edge (weight, graph) ----------------
__global__ void k_fill_csr(const int* __restrict__ src, const int* __restrict__ dst,
                           const int* __restrict__ batch, const float* __restrict__ invdeg,
                           const int* __restrict__ rowptr, int* __restrict__ pos,
                           int* __restrict__ col, float* __restrict__ eW,
                           int* __restrict__ eG, int E) {
    int e = blockIdx.x * blockDim.x + threadIdx.x;
    if (e >= E) return;
    int d = dst[e];
    int slot = rowptr[d] + atomicAdd(&pos[d], 1);
    col[slot] = src[e];
    eW[e] = invdeg[d];
    eG[e] = batch[d];
}

// ---------------- layer-1 aggregation: one wave per node ----------------
__global__ __launch_bounds__(256) void k_agg1(const float* __restrict__ x,
                                              const int* __restrict__ rowptr,
                                              const int* __restrict__ col,
                                              const float* __restrict__ invdeg,
                                              float* __restrict__ agg, int N) {
    int wave = (int)((blockIdx.x * blockDim.x + threadIdx.x) >> 6);
    int lane = threadIdx.x & 63;
    if (wave >= N) return;
    int lo = rowptr[wave], hi = rowptr[wave + 1];
    float ax = 0.f, ay = 0.f;
    for (int j = lo; j < hi; j++) {
        int s = col[j];
        float2 v = *(const float2*)&x[(size_t)s * IN_C + lane * 2];
        ax += v.x; ay += v.y;
    }
    float w = invdeg[wave];
    float2 o; o.x = ax * w; o.y = ay * w;
    *(float2*)&agg[(size_t)wave * IN_C + lane * 2] = o;
}

// ---------------- fused GEMM1 + bias + BN(eval) + ReLU ----------------
// h1[n][c] = relu(bn(x[n]@W1r + agg[n]@W1a + b1))   tile: 16 nodes x 256 ch
__global__ __launch_bounds__(256) void k_gemm1(const float* __restrict__ x,
                                               const float* __restrict__ agg,
                                               const float* __restrict__ W1r,
                                               const float* __restrict__ W1a,
                                               const float* __restrict__ b1,
                                               const float* __restrict__ gamma,
                                               const float* __restrict__ beta,
                                               const float* __restrict__ mean,
                                               const float* __restrict__ var,
                                               float* __restrict__ h1, int N) {
    __shared__ float Ax[16 * 128];
    __shared__ float Ag[16 * 128];
    int n0 = blockIdx.x * 16;
    int t = threadIdx.x;
    for (int i = t; i < 512; i += 256) {       // 512 float4 loads per array
        int row = i >> 5, c4 = i & 31;
        int n = min(n0 + row, N - 1);
        *(float4*)&Ax[row * 128 + c4 * 4] = *(const float4*)&x[(size_t)n * 128 + c4 * 4];
        *(float4*)&Ag[row * 128 + c4 * 4] = *(const float4*)&agg[(size_t)n * 128 + c4 * 4];
    }
    __syncthreads();
    int cg = t & 63;       // channel group: channels 4*cg .. 4*cg+3
    int mg = t >> 6;       // node group:    nodes   mg*4 .. mg*4+3
    float acc[4][4];
#pragma unroll
    for (int i = 0; i < 4; i++)
#pragma unroll
        for (int j = 0; j < 4; j++) acc[i][j] = 0.f;

    const float* Axp = &Ax[(mg * 4) * 128];
    const float* Agp = &Ag[(mg * 4) * 128];
    for (int k = 0; k < 128; k++) {
        float4 w = *(const float4*)&W1r[k * 256 + cg * 4];
#pragma unroll
        for (int i = 0; i < 4; i++) {
            float a = Axp[i * 128 + k];
            acc[i][0] += a * w.x; acc[i][1] += a * w.y;
            acc[i][2] += a * w.z; acc[i][3] += a * w.w;
        }
    }
    for (int k = 0; k < 128; k++) {
        float4 w = *(const float4*)&W1a[k * 256 + cg * 4];
#pragma unroll
        for (int i = 0; i < 4; i++) {
            float a = Agp[i * 128 + k];
            acc[i][0] += a * w.x; acc[i][1] += a * w.y;
            acc[i][2] += a * w.z; acc[i][3] += a * w.w;
        }
    }
    float4 bb = *(const float4*)&b1[cg * 4];
    float4 gm = *(const float4*)&gamma[cg * 4];
    float4 bt = *(const float4*)&beta[cg * 4];
    float4 mn = *(const float4*)&mean[cg * 4];
    float4 vr = *(const float4*)&var[cg * 4];
    float s0 = gm.x * rsqrtf(vr.x + BN_EPS);
    float s1 = gm.y * rsqrtf(vr.y + BN_EPS);
    float s2 = gm.z * rsqrtf(vr.z + BN_EPS);
    float s3 = gm.w * rsqrtf(vr.w + BN_EPS);
#pragma unroll
    for (int i = 0; i < 4; i++) {
        int n = n0 + mg * 4 + i;
        if (n < N) {
            float4 o;
            o.x = fmaxf((acc[i][0] + bb.x - mn.x) * s0 + bt.x, 0.f);
            o.y = fmaxf((acc[i][1] + bb.y - mn.y) * s1 + bt.y, 0.f);
            o.z = fmaxf((acc[i][2] + bb.z - mn.z) * s2 + bt.z, 0.f);
            o.w = fmaxf((acc[i][3] + bb.w - mn.w) * s3 + bt.w, 0.f);
            *(float4*)&h1[(size_t)n * 256 + cg * 4] = o;
        }
    }
}

// ---------------- P1[g][c] = sum of h1 rows per graph (batch sorted) ----------------
__global__ __launch_bounds__(256) void k_p1(const float* __restrict__ h1,
                                            const int* __restrict__ batch,
                                            float* __restrict__ P1,
                                            float* __restrict__ cnt, int N) {
    int n0 = blockIdx.x * 64;
    if (n0 >= N) return;
    int n1 = min(n0 + 64, N);
    int t = threadIdx.x;
    float racc = 0.f;
    int count = 0;
    int curg = batch[n0];
    for (int n = n0; n < n1; n++) {
        int g = batch[n];
        if (g != curg) {
            atomicAdd(&P1[curg * 256 + t], racc);
            if (t == 0) atomicAdd(&cnt[curg], (float)count);
            racc = 0.f; count = 0; curg = g;
        }
        racc += h1[(size_t)n * 256 + t];
        count++;
    }
    atomicAdd(&P1[curg * 256 + t], racc);
    if (t == 0) atomicAdd(&cnt[curg], (float)count);
}

// ---------------- P2[g][c] = sum_e h1[src[e]][c] * invdeg[dst[e]], grouped by batch[dst[e]]
__global__ __launch_bounds__(256) void k_p2(const float* __restrict__ h1,
                                            const int* __restrict__ src,
                                            const float* __restrict__ eW,
                                            const int* __restrict__ eG,
                                            float* __restrict__ P2, int E) {
    __shared__ float acc[N_GRAPHS * 256];
    int t = threadIdx.x;
    for (int g = 0; g < N_GRAPHS; g++) acc[g * 256 + t] = 0.f;
    int per = (E + gridDim.x - 1) / gridDim.x;
    int e0 = blockIdx.x * per;
    int e1 = min(e0 + per, E);
    for (int e = e0; e < e1; e++) {
        int s = src[e];
        float w = eW[e];
        int g = eG[e];
        acc[g * 256 + t] += h1[(size_t)s * 256 + t] * w;
    }
    for (int g = 0; g < N_GRAPHS; g++) atomicAdd(&P2[g * 256 + t], acc[g * 256 + t]);
}

// ---------------- classifier: one block per graph ----------------
__global__ __launch_bounds__(256) void k_classifier(
        const float* __restrict__ P1, const float* __restrict__ P2,
        const float* __restrict__ cnt,
        const float* __restrict__ W2a, const float* __restrict__ W2r,
        const float* __restrict__ b2,
        const float* __restrict__ Wc1, const float* __restrict__ bc1,
        const float* __restrict__ Wc2, const float* __restrict__ bc2,
        float* __restrict__ out) {
    __shared__ float p1s[256], p2s[256], g2[256], c1s[128], lg[2];
    int g = blockIdx.x, t = threadIdx.x;
    p1s[t] = P1[g * 256 + t];
    p2s[t] = P2[g * 256 + t];
    __syncthreads();
    float acc = 0.f;
    for (int k = 0; k < 256; k++)
        acc += p2s[k] * W2a[k * 256 + t] + p1s[k] * W2r[k * 256 + t];
    float c = cnt[g];
    float inv = 1.0f / fmaxf(c, 1.0f);
    g2[t] = (acc + c * b2[t]) * inv;   // empty graph -> exactly 0 (matches ref)
    __syncthreads();
    if (t < 128) {
        float a = bc1[t];
        for (int k = 0; k < 256; k++) a += g2[k] * Wc1[k * 128 + t];
        c1s[t] = fmaxf(a, 0.f);
    }
    __syncthreads();
    if (t < 2) {
        float a = bc2[t];
        for (int k = 0; k < 128; k++) a += c1s[k] * Wc2[k * 2 + t];
        lg[t] = a;
    }
    __syncthreads();
    if (t == 0) {
        float m = fmaxf(lg[0], lg[1]);
        float lse = m + logf(expf(lg[0] - m) + expf(lg[1] - m));
        out[g * 2 + 0] = lg[0] - lse;
        out[g * 2 + 1] = lg[1] - lse;
    }
}

extern "C" void kernel_launch(void* const* d_in, const int* in_sizes, int n_in,
                              void* d_out, int out_size, void* d_ws, size_t ws_size,
                              hipStream_t stream) {
    const float* x     = (const float*)d_in[0];
    const int*   edge  = (const int*)d_in[1];
    const int*   batch = (const int*)d_in[2];
    const float* W1a   = (const float*)d_in[3];
    const float* W1r   = (const float*)d_in[4];
    const float* b1    = (const float*)d_in[5];
    const float* gamma = (const float*)d_in[6];
    const float* beta  = (const float*)d_in[7];
    const float* mean  = (const float*)d_in[8];
    const float* var   = (const float*)d_in[9];
    const float* W2a   = (const float*)d_in[10];
    const float* W2r   = (const float*)d_in[11];
    const float* b2    = (const float*)d_in[12];
    const float* Wc1   = (const float*)d_in[13];
    const float* bc1   = (const float*)d_in[14];
    const float* Wc2   = (const float*)d_in[15];
    const float* bc2   = (const float*)d_in[16];
    float* out = (float*)d_out;

    const int N = N_NODES;
    const int E = in_sizes[1] / 2;
    const int* src = edge;
    const int* dst = edge + E;

    // workspace carve (256-B aligned regions)
    char* wsp = (char*)d_ws;
    auto alloc = [&](size_t bytes) {
        char* p = wsp;
        wsp += (bytes + 255) & ~(size_t)255;
        return p;
    };
    int*   deg    = (int*)alloc((size_t)N * 4);
    int*   pos    = (int*)alloc((size_t)N * 4);
    float* P1     = (float*)alloc((size_t)N_GRAPHS * 256 * 4);
    float* P2     = (float*)alloc((size_t)N_GRAPHS * 256 * 4);
    float* cnt    = (float*)alloc(256 * 4);
    char*  zero_end = wsp;
    int*   rowptr = (int*)alloc((size_t)(N + 1) * 4);
    float* invdeg = (float*)alloc((size_t)N * 4);
    int*   col    = (int*)alloc((size_t)E * 4);
    float* eW     = (float*)alloc((size_t)E * 4);
    int*   eG     = (int*)alloc((size_t)E * 4);
    float* agg1   = (float*)alloc((size_t)N * IN_C * 4);
    float* h1     = (float*)alloc((size_t)N * HID * 4);

    // zero the accumulator regions (deg, pos, P1, P2, cnt are contiguous)
    hipMemsetAsync(deg, 0, (size_t)(zero_end - (char*)deg), stream);

    k_count_deg<<<(E + 255) / 256, 256, 0, stream>>>(dst, deg, E);
    k_scan<<<1, 1024, 0, stream>>>(deg, rowptr, invdeg, N);
    k_fill_csr<<<(E + 255) / 256, 256, 0, stream>>>(src, dst, batch, invdeg, rowptr,
                                                    pos, col, eW, eG, E);
    k_agg1<<<(N + 3) / 4, 256, 0, stream>>>(x, rowptr, col, invdeg, agg1, N);
    k_gemm1<<<(N + 15) / 16, 256, 0, stream>>>(x, agg1, W1r, W1a, b1, gamma, beta,
                                               mean, var, h1, N);
    k_p1<<<(N + 63) / 64, 256, 0, stream>>>(h1, batch, P1, cnt, N);
    k_p2<<<512, 256, 0, stream>>>(h1, src, eW, eG, P2, E);
    k_classifier<<<N_GRAPHS, 256, 0, stream>>>(P1, P2, cnt, W2a, W2r, b2,
                                               Wc1, bc1, Wc2, bc2, out);
}

// Round 2
// 937.575 us; speedup vs baseline: 1.3032x; 1.3032x over previous
//
#include <hip/hip_runtime.h>
#include <math.h>

#define N_NODES 100000
#define IN_C 128
#define HID 256
#define N_GRAPHS 64
#define BN_EPS 1e-5f

// ---------------- degree count ----------------
__global__ void k_count_deg(const int* __restrict__ dst, int* __restrict__ deg, int E) {
    int e = blockIdx.x * blockDim.x + threadIdx.x;
    if (e < E) atomicAdd(&deg[dst[e]], 1);
}

// ---------------- single-block exclusive scan -> rowptr, invdeg ----------------
__global__ __launch_bounds__(1024) void k_scan(const int* __restrict__ deg,
                                               int* __restrict__ rowptr,
                                               float* __restrict__ invdeg, int N) {
    __shared__ int part[1024];
    int t = threadIdx.x;
    int chunk = (N + 1023) / 1024;
    int lo = t * chunk;
    int hi = min(lo + chunk, N);
    int s = 0;
    for (int i = lo; i < hi; i++) s += deg[i];
    part[t] = s;
    __syncthreads();
    for (int off = 1; off < 1024; off <<= 1) {
        int v = (t >= off) ? part[t - off] : 0;
        __syncthreads();
        part[t] += v;
        __syncthreads();
    }
    int run = (t == 0) ? 0 : part[t - 1];
    for (int i = lo; i < hi; i++) {
        rowptr[i] = run;
        int d = deg[i];
        run += d;
        invdeg[i] = 1.0f / (float)max(d, 1);
    }
    if (t == 1023) rowptr[N] = part[1023];
}

// ---------------- fill CSR + per-slot (weight, graph) in CSR order ----------------
// eG written at CSR slot => non-decreasing across slots (rows ordered by node,
// batch sorted by node). k_p2 exploits this for register accumulation.
__global__ void k_fill_csr(const int* __restrict__ src, const int* __restrict__ dst,
                           const int* __restrict__ batch, const float* __restrict__ invdeg,
                           const int* __restrict__ rowptr, int* __restrict__ pos,
                           int* __restrict__ col, float* __restrict__ eW,
                           int* __restrict__ eG, int E) {
    int e = blockIdx.x * blockDim.x + threadIdx.x;
    if (e >= E) return;
    int d = dst[e];
    int slot = rowptr[d] + atomicAdd(&pos[d], 1);
    col[slot] = src[e];
    eW[slot] = invdeg[d];
    eG[slot] = batch[d];
}

// ---------------- layer-1 aggregation: one wave per node ----------------
__global__ __launch_bounds__(256) void k_agg1(const float* __restrict__ x,
                                              const int* __restrict__ rowptr,
                                              const int* __restrict__ col,
                                              const float* __restrict__ invdeg,
                                              float* __restrict__ agg, int N) {
    int wave = (int)((blockIdx.x * blockDim.x + threadIdx.x) >> 6);
    int lane = threadIdx.x & 63;
    if (wave >= N) return;
    int lo = rowptr[wave], hi = rowptr[wave + 1];
    float ax = 0.f, ay = 0.f;
    for (int j = lo; j < hi; j++) {
        int s = col[j];
        float2 v = *(const float2*)&x[(size_t)s * IN_C + lane * 2];
        ax += v.x; ay += v.y;
    }
    float w = invdeg[wave];
    float2 o; o.x = ax * w; o.y = ay * w;
    *(float2*)&agg[(size_t)wave * IN_C + lane * 2] = o;
}

// ---------------- fused GEMM1 + bias + BN(eval) + ReLU ----------------
__global__ __launch_bounds__(256) void k_gemm1(const float* __restrict__ x,
                                               const float* __restrict__ agg,
                                               const float* __restrict__ W1r,
                                               const float* __restrict__ W1a,
                                               const float* __restrict__ b1,
                                               const float* __restrict__ gamma,
                                               const float* __restrict__ beta,
                                               const float* __restrict__ mean,
                                               const float* __restrict__ var,
                                               float* __restrict__ h1, int N) {
    __shared__ float Ax[16 * 128];
    __shared__ float Ag[16 * 128];
    int n0 = blockIdx.x * 16;
    int t = threadIdx.x;
    for (int i = t; i < 512; i += 256) {
        int row = i >> 5, c4 = i & 31;
        int n = min(n0 + row, N - 1);
        *(float4*)&Ax[row * 128 + c4 * 4] = *(const float4*)&x[(size_t)n * 128 + c4 * 4];
        *(float4*)&Ag[row * 128 + c4 * 4] = *(const float4*)&agg[(size_t)n * 128 + c4 * 4];
    }
    __syncthreads();
    int cg = t & 63;
    int mg = t >> 6;
    float acc[4][4];
#pragma unroll
    for (int i = 0; i < 4; i++)
#pragma unroll
        for (int j = 0; j < 4; j++) acc[i][j] = 0.f;

    const float* Axp = &Ax[(mg * 4) * 128];
    const float* Agp = &Ag[(mg * 4) * 128];
    for (int k = 0; k < 128; k++) {
        float4 w = *(const float4*)&W1r[k * 256 + cg * 4];
#pragma unroll
        for (int i = 0; i < 4; i++) {
            float a = Axp[i * 128 + k];
            acc[i][0] += a * w.x; acc[i][1] += a * w.y;
            acc[i][2] += a * w.z; acc[i][3] += a * w.w;
        }
    }
    for (int k = 0; k < 128; k++) {
        float4 w = *(const float4*)&W1a[k * 256 + cg * 4];
#pragma unroll
        for (int i = 0; i < 4; i++) {
            float a = Agp[i * 128 + k];
            acc[i][0] += a * w.x; acc[i][1] += a * w.y;
            acc[i][2] += a * w.z; acc[i][3] += a * w.w;
        }
    }
    float4 bb = *(const float4*)&b1[cg * 4];
    float4 gm = *(const float4*)&gamma[cg * 4];
    float4 bt = *(const float4*)&beta[cg * 4];
    float4 mn = *(const float4*)&mean[cg * 4];
    float4 vr = *(const float4*)&var[cg * 4];
    float s0 = gm.x * rsqrtf(vr.x + BN_EPS);
    float s1 = gm.y * rsqrtf(vr.y + BN_EPS);
    float s2 = gm.z * rsqrtf(vr.z + BN_EPS);
    float s3 = gm.w * rsqrtf(vr.w + BN_EPS);
#pragma unroll
    for (int i = 0; i < 4; i++) {
        int n = n0 + mg * 4 + i;
        if (n < N) {
            float4 o;
            o.x = fmaxf((acc[i][0] + bb.x - mn.x) * s0 + bt.x, 0.f);
            o.y = fmaxf((acc[i][1] + bb.y - mn.y) * s1 + bt.y, 0.f);
            o.z = fmaxf((acc[i][2] + bb.z - mn.z) * s2 + bt.z, 0.f);
            o.w = fmaxf((acc[i][3] + bb.w - mn.w) * s3 + bt.w, 0.f);
            *(float4*)&h1[(size_t)n * 256 + cg * 4] = o;
        }
    }
}

// ---------------- P1[g][c] = sum of h1 rows per graph (batch sorted) ----------------
__global__ __launch_bounds__(256) void k_p1(const float* __restrict__ h1,
                                            const int* __restrict__ batch,
                                            float* __restrict__ P1,
                                            float* __restrict__ cnt, int N) {
    int n0 = blockIdx.x * 64;
    if (n0 >= N) return;
    int n1 = min(n0 + 64, N);
    int t = threadIdx.x;
    float racc = 0.f;
    int count = 0;
    int curg = batch[n0];
    for (int n = n0; n < n1; n++) {
        int g = batch[n];
        if (g != curg) {
            atomicAdd(&P1[curg * 256 + t], racc);
            if (t == 0) atomicAdd(&cnt[curg], (float)count);
            racc = 0.f; count = 0; curg = g;
        }
        racc += h1[(size_t)n * 256 + t];
        count++;
    }
    atomicAdd(&P1[curg * 256 + t], racc);
    if (t == 0) atomicAdd(&cnt[curg], (float)count);
}

// ---------------- P2[g][c] via CSR-ordered edges: register accumulate ----------------
// eG non-decreasing in slot order => per-block contiguous edge range spans few
// graphs; accumulate in a register, flush on graph change (rare, wave-uniform).
// 8 independent gathers in flight per thread.
__global__ __launch_bounds__(256) void k_p2(const float* __restrict__ h1,
                                            const int* __restrict__ col,
                                            const float* __restrict__ eW,
                                            const int* __restrict__ eG,
                                            float* __restrict__ P2, int E) {
    int t = threadIdx.x;
    int per = (E + gridDim.x - 1) / gridDim.x;
    int e0 = blockIdx.x * per;
    int e1 = min(e0 + per, E);
    if (e0 >= e1) return;
    float racc = 0.f;
    int curg = eG[e0];
    int e = e0;
    while (e < e1) {
        if (e + 8 <= e1 && eG[e + 7] == curg) {   // uniform fast path: 8 same-graph edges
            int   s0 = col[e + 0], s1 = col[e + 1], s2 = col[e + 2], s3 = col[e + 3];
            int   s4 = col[e + 4], s5 = col[e + 5], s6 = col[e + 6], s7 = col[e + 7];
            float v0 = h1[(size_t)s0 * 256 + t] * eW[e + 0];
            float v1 = h1[(size_t)s1 * 256 + t] * eW[e + 1];
            float v2 = h1[(size_t)s2 * 256 + t] * eW[e + 2];
            float v3 = h1[(size_t)s3 * 256 + t] * eW[e + 3];
            float v4 = h1[(size_t)s4 * 256 + t] * eW[e + 4];
            float v5 = h1[(size_t)s5 * 256 + t] * eW[e + 5];
            float v6 = h1[(size_t)s6 * 256 + t] * eW[e + 6];
            float v7 = h1[(size_t)s7 * 256 + t] * eW[e + 7];
            racc += ((v0 + v1) + (v2 + v3)) + ((v4 + v5) + (v6 + v7));
            e += 8;
        } else {
            int g = eG[e];
            if (g != curg) {
                atomicAdd(&P2[curg * 256 + t], racc);
                racc = 0.f;
                curg = g;
            }
            racc += h1[(size_t)col[e] * 256 + t] * eW[e];
            e++;
        }
    }
    atomicAdd(&P2[curg * 256 + t], racc);
}

// ---------------- classifier: one block per graph ----------------
__global__ __launch_bounds__(256) void k_classifier(
        const float* __restrict__ P1, const float* __restrict__ P2,
        const float* __restrict__ cnt,
        const float* __restrict__ W2a, const float* __restrict__ W2r,
        const float* __restrict__ b2,
        const float* __restrict__ Wc1, const float* __restrict__ bc1,
        const float* __restrict__ Wc2, const float* __restrict__ bc2,
        float* __restrict__ out) {
    __shared__ float p1s[256], p2s[256], g2[256], c1s[128], lg[2];
    int g = blockIdx.x, t = threadIdx.x;
    p1s[t] = P1[g * 256 + t];
    p2s[t] = P2[g * 256 + t];
    __syncthreads();
    float acc = 0.f;
    for (int k = 0; k < 256; k++)
        acc += p2s[k] * W2a[k * 256 + t] + p1s[k] * W2r[k * 256 + t];
    float c = cnt[g];
    float inv = 1.0f / fmaxf(c, 1.0f);
    g2[t] = (acc + c * b2[t]) * inv;
    __syncthreads();
    if (t < 128) {
        float a = bc1[t];
        for (int k = 0; k < 256; k++) a += g2[k] * Wc1[k * 128 + t];
        c1s[t] = fmaxf(a, 0.f);
    }
    __syncthreads();
    if (t < 2) {
        float a = bc2[t];
        for (int k = 0; k < 128; k++) a += c1s[k] * Wc2[k * 2 + t];
        lg[t] = a;
    }
    __syncthreads();
    if (t == 0) {
        float m = fmaxf(lg[0], lg[1]);
        float lse = m + logf(expf(lg[0] - m) + expf(lg[1] - m));
        out[g * 2 + 0] = lg[0] - lse;
        out[g * 2 + 1] = lg[1] - lse;
    }
}

extern "C" void kernel_launch(void* const* d_in, const int* in_sizes, int n_in,
                              void* d_out, int out_size, void* d_ws, size_t ws_size,
                              hipStream_t stream) {
    const float* x     = (const float*)d_in[0];
    const int*   edge  = (const int*)d_in[1];
    const int*   batch = (const int*)d_in[2];
    const float* W1a   = (const float*)d_in[3];
    const float* W1r   = (const float*)d_in[4];
    const float* b1    = (const float*)d_in[5];
    const float* gamma = (const float*)d_in[6];
    const float* beta  = (const float*)d_in[7];
    const float* mean  = (const float*)d_in[8];
    const float* var   = (const float*)d_in[9];
    const float* W2a   = (const float*)d_in[10];
    const float* W2r   = (const float*)d_in[11];
    const float* b2    = (const float*)d_in[12];
    const float* Wc1   = (const float*)d_in[13];
    const float* bc1   = (const float*)d_in[14];
    const float* Wc2   = (const float*)d_in[15];
    const float* bc2   = (const float*)d_in[16];
    float* out = (float*)d_out;

    const int N = N_NODES;
    const int E = in_sizes[1] / 2;
    const int* src = edge;
    const int* dst = edge + E;

    char* wsp = (char*)d_ws;
    auto alloc = [&](size_t bytes) {
        char* p = wsp;
        wsp += (bytes + 255) & ~(size_t)255;
        return p;
    };
    int*   deg    = (int*)alloc((size_t)N * 4);
    int*   pos    = (int*)alloc((size_t)N * 4);
    float* P1     = (float*)alloc((size_t)N_GRAPHS * 256 * 4);
    float* P2     = (float*)alloc((size_t)N_GRAPHS * 256 * 4);
    float* cnt    = (float*)alloc(256 * 4);
    char*  zero_end = wsp;
    int*   rowptr = (int*)alloc((size_t)(N + 1) * 4);
    float* invdeg = (float*)alloc((size_t)N * 4);
    int*   col    = (int*)alloc((size_t)E * 4);
    float* eW     = (float*)alloc((size_t)E * 4);
    int*   eG     = (int*)alloc((size_t)E * 4);
    float* agg1   = (float*)alloc((size_t)N * IN_C * 4);
    float* h1     = (float*)alloc((size_t)N * HID * 4);

    hipMemsetAsync(deg, 0, (size_t)(zero_end - (char*)deg), stream);

    k_count_deg<<<(E + 255) / 256, 256, 0, stream>>>(dst, deg, E);
    k_scan<<<1, 1024, 0, stream>>>(deg, rowptr, invdeg, N);
    k_fill_csr<<<(E + 255) / 256, 256, 0, stream>>>(src, dst, batch, invdeg, rowptr,
                                                    pos, col, eW, eG, E);
    k_agg1<<<(N + 3) / 4, 256, 0, stream>>>(x, rowptr, col, invdeg, agg1, N);
    k_gemm1<<<(N + 15) / 16, 256, 0, stream>>>(x, agg1, W1r, W1a, b1, gamma, beta,
                                               mean, var, h1, N);
    k_p1<<<(N + 63) / 64, 256, 0, stream>>>(h1, batch, P1, cnt, N);
    k_p2<<<2048, 256, 0, stream>>>(h1, col, eW, eG, P2, E);
    k_classifier<<<N_GRAPHS, 256, 0, stream>>>(P1, P2, cnt, W2a, W2r, b2,
                                               Wc1, bc1, Wc2, bc2, out);
}

// Round 3
// 702.115 us; speedup vs baseline: 1.7402x; 1.3354x over previous
//
#include <hip/hip_runtime.h>
#include <math.h>

#define N_NODES 100000
#define IN_C 128
#define HID 256
#define N_GRAPHS 64
#define BN_EPS 1e-5f

typedef unsigned int   uint32;
typedef unsigned short ushort16;
typedef __attribute__((ext_vector_type(8))) short bf16x8;
typedef __attribute__((ext_vector_type(4))) float f32x4;

__device__ __forceinline__ float bf_lo(uint32 u) { return __builtin_bit_cast(float, u << 16); }
__device__ __forceinline__ float bf_hi(uint32 u) { return __builtin_bit_cast(float, u & 0xffff0000u); }
__device__ __forceinline__ ushort16 f2bf(float f) {   // round-to-nearest-even
    uint32 u = __builtin_bit_cast(uint32, f);
    return (ushort16)((u + 0x7fffu + ((u >> 16) & 1u)) >> 16);
}

// ---------------- degree count ----------------
__global__ void k_count_deg(const int* __restrict__ dst, int* __restrict__ deg, int E) {
    int e = blockIdx.x * blockDim.x + threadIdx.x;
    if (e < E) atomicAdd(&deg[dst[e]], 1);
}

// ---------------- x fp32 -> bf16 ----------------
__global__ void k_cvt_x(const float4* __restrict__ x4, ushort4* __restrict__ xb4, int n4) {
    int i = blockIdx.x * blockDim.x + threadIdx.x;
    if (i >= n4) return;
    float4 v = x4[i];
    ushort4 o;
    o.x = f2bf(v.x); o.y = f2bf(v.y); o.z = f2bf(v.z); o.w = f2bf(v.w);
    xb4[i] = o;
}

// ---------------- build WT hi/lo: WT[c][k] = Wcat[k][c], split-bf16 ----------------
__global__ void k_prep_w(const float* __restrict__ W1r, const float* __restrict__ W1a,
                         ushort16* __restrict__ WThi, ushort16* __restrict__ WTlo) {
    int c = blockIdx.x;     // out channel 0..255
    int k = threadIdx.x;    // input k 0..255
    float v = (k < 128) ? W1r[(size_t)k * 256 + c] : W1a[(size_t)(k - 128) * 256 + c];
    ushort16 h = f2bf(v);
    float vh = __builtin_bit_cast(float, ((uint32)h) << 16);
    ushort16 l = f2bf(v - vh);
    WThi[c * 256 + k] = h;
    WTlo[c * 256 + k] = l;
}

// ---------------- single-block exclusive scan -> rowptr, invdeg ----------------
__global__ __launch_bounds__(1024) void k_scan(const int* __restrict__ deg,
                                               int* __restrict__ rowptr,
                                               float* __restrict__ invdeg, int N) {
    __shared__ int part[1024];
    int t = threadIdx.x;
    int chunk = (N + 1023) / 1024;
    int lo = t * chunk;
    int hi = min(lo + chunk, N);
    int s = 0;
    for (int i = lo; i < hi; i++) s += deg[i];
    part[t] = s;
    __syncthreads();
    for (int off = 1; off < 1024; off <<= 1) {
        int v = (t >= off) ? part[t - off] : 0;
        __syncthreads();
        part[t] += v;
        __syncthreads();
    }
    int run = (t == 0) ? 0 : part[t - 1];
    for (int i = lo; i < hi; i++) {
        rowptr[i] = run;
        int d = deg[i];
        run += d;
        invdeg[i] = 1.0f / (float)max(d, 1);
    }
    if (t == 1023) rowptr[N] = part[1023];
}

// ---------------- fill CSR (slot-ordered eW/eG => eG non-decreasing) ----------------
__global__ void k_fill_csr(const int* __restrict__ src, const int* __restrict__ dst,
                           const int* __restrict__ batch, const float* __restrict__ invdeg,
                           const int* __restrict__ rowptr, int* __restrict__ pos,
                           int* __restrict__ col, float* __restrict__ eW,
                           int* __restrict__ eG, int E) {
    int e = blockIdx.x * blockDim.x + threadIdx.x;
    if (e >= E) return;
    int d = dst[e];
    int slot = rowptr[d] + atomicAdd(&pos[d], 1);
    col[slot] = src[e];
    eW[slot] = invdeg[d];
    eG[slot] = batch[d];
}

// ---------------- layer-1 aggregation (bf16 in/out): one wave per node ----------------
__global__ __launch_bounds__(256) void k_agg1(const uint32* __restrict__ xb2,
                                              const int* __restrict__ rowptr,
                                              const int* __restrict__ col,
                                              const float* __restrict__ invdeg,
                                              uint32* __restrict__ aggb2, int N) {
    int wave = (int)((blockIdx.x * blockDim.x + threadIdx.x) >> 6);
    int lane = threadIdx.x & 63;
    if (wave >= N) return;
    int lo = rowptr[wave], hi = rowptr[wave + 1];
    float ax = 0.f, ay = 0.f;
    int j = lo;
    for (; j + 4 <= hi; j += 4) {
        int s0 = col[j], s1 = col[j + 1], s2 = col[j + 2], s3 = col[j + 3];
        uint32 u0 = xb2[(size_t)s0 * 64 + lane];
        uint32 u1 = xb2[(size_t)s1 * 64 + lane];
        uint32 u2 = xb2[(size_t)s2 * 64 + lane];
        uint32 u3 = xb2[(size_t)s3 * 64 + lane];
        ax += (bf_lo(u0) + bf_lo(u1)) + (bf_lo(u2) + bf_lo(u3));
        ay += (bf_hi(u0) + bf_hi(u1)) + (bf_hi(u2) + bf_hi(u3));
    }
    for (; j < hi; j++) {
        uint32 u = xb2[(size_t)col[j] * 64 + lane];
        ax += bf_lo(u); ay += bf_hi(u);
    }
    float w = invdeg[wave];
    uint32 p = (uint32)f2bf(ax * w) | (((uint32)f2bf(ay * w)) << 16);
    aggb2[(size_t)wave * 64 + lane] = p;
}

// ---------------- fused MFMA GEMM1 + bias + BN(eval) + ReLU -> h1 bf16 ----------------
// D[channel][node]: A-op = WT tile (16 ch x 32 k), B-op = node tile (32 k x 16 nodes).
// Block: 64 nodes x 256 channels; wave w owns channels w*64..w*64+63.
__global__ __launch_bounds__(256) void k_gemm1(
        const ushort16* __restrict__ xb, const ushort16* __restrict__ aggb,
        const ushort16* __restrict__ WThi, const ushort16* __restrict__ WTlo,
        const float* __restrict__ b1, const float* __restrict__ gamma,
        const float* __restrict__ beta, const float* __restrict__ mean,
        const float* __restrict__ var, ushort16* __restrict__ h1, int N) {
    int n0 = blockIdx.x * 64;
    int w = threadIdx.x >> 6;
    int l = threadIdx.x & 63;
    int l15 = l & 15;
    int lg = l >> 4;
    int ocb = w * 64;

    f32x4 acc[4][4];
#pragma unroll
    for (int i = 0; i < 4; i++)
#pragma unroll
        for (int j = 0; j < 4; j++) acc[i][j] = (f32x4)0.f;

    int nidx[4];
#pragma unroll
    for (int nt = 0; nt < 4; nt++) nidx[nt] = min(n0 + nt * 16 + l15, N - 1);

    const ushort16* wrh[4];
    const ushort16* wrl[4];
#pragma unroll
    for (int ot = 0; ot < 4; ot++) {
        size_t off = (size_t)(ocb + ot * 16 + l15) * 256 + lg * 8;
        wrh[ot] = WThi + off;
        wrl[ot] = WTlo + off;
    }

    // K 0..127 : x part
#pragma unroll
    for (int ks = 0; ks < 4; ks++) {
        int k0 = ks * 32;
        bf16x8 wh[4], wl[4], bx[4];
#pragma unroll
        for (int ot = 0; ot < 4; ot++) {
            wh[ot] = *(const bf16x8*)(wrh[ot] + k0);
            wl[ot] = *(const bf16x8*)(wrl[ot] + k0);
        }
#pragma unroll
        for (int nt = 0; nt < 4; nt++)
            bx[nt] = *(const bf16x8*)(xb + (size_t)nidx[nt] * 128 + k0 + lg * 8);
#pragma unroll
        for (int ot = 0; ot < 4; ot++)
#pragma unroll
            for (int nt = 0; nt < 4; nt++) {
                acc[ot][nt] = __builtin_amdgcn_mfma_f32_16x16x32_bf16(wh[ot], bx[nt], acc[ot][nt], 0, 0, 0);
                acc[ot][nt] = __builtin_amdgcn_mfma_f32_16x16x32_bf16(wl[ot], bx[nt], acc[ot][nt], 0, 0, 0);
            }
    }
    // K 128..255 : agg part
#pragma unroll
    for (int ks = 0; ks < 4; ks++) {
        int k0 = 128 + ks * 32;
        bf16x8 wh[4], wl[4], bx[4];
#pragma unroll
        for (int ot = 0; ot < 4; ot++) {
            wh[ot] = *(const bf16x8*)(wrh[ot] + k0);
            wl[ot] = *(const bf16x8*)(wrl[ot] + k0);
        }
#pragma unroll
        for (int nt = 0; nt < 4; nt++)
            bx[nt] = *(const bf16x8*)(aggb + (size_t)nidx[nt] * 128 + ks * 32 + lg * 8);
#pragma unroll
        for (int ot = 0; ot < 4; ot++)
#pragma unroll
            for (int nt = 0; nt < 4; nt++) {
                acc[ot][nt] = __builtin_amdgcn_mfma_f32_16x16x32_bf16(wh[ot], bx[nt], acc[ot][nt], 0, 0, 0);
                acc[ot][nt] = __builtin_amdgcn_mfma_f32_16x16x32_bf16(wl[ot], bx[nt], acc[ot][nt], 0, 0, 0);
            }
    }

    // epilogue: channel c = ocb + ot*16 + lg*4 + r, node = n0 + nt*16 + l15
#pragma unroll
    for (int ot = 0; ot < 4; ot++) {
        int c = ocb + ot * 16 + lg * 4;
        float4 gm = *(const float4*)&gamma[c];
        float4 bt = *(const float4*)&beta[c];
        float4 mn = *(const float4*)&mean[c];
        float4 vr = *(const float4*)&var[c];
        float4 bb = *(const float4*)&b1[c];
        float s0 = gm.x * rsqrtf(vr.x + BN_EPS);
        float s1 = gm.y * rsqrtf(vr.y + BN_EPS);
        float s2 = gm.z * rsqrtf(vr.z + BN_EPS);
        float s3 = gm.w * rsqrtf(vr.w + BN_EPS);
        float o0 = bt.x + (bb.x - mn.x) * s0;
        float o1 = bt.y + (bb.y - mn.y) * s1;
        float o2 = bt.z + (bb.z - mn.z) * s2;
        float o3 = bt.w + (bb.w - mn.w) * s3;
#pragma unroll
        for (int nt = 0; nt < 4; nt++) {
            int n = n0 + nt * 16 + l15;
            if (n < N) {
                f32x4 a = acc[ot][nt];
                ushort4 pk;
                pk.x = f2bf(fmaxf(a[0] * s0 + o0, 0.f));
                pk.y = f2bf(fmaxf(a[1] * s1 + o1, 0.f));
                pk.z = f2bf(fmaxf(a[2] * s2 + o2, 0.f));
                pk.w = f2bf(fmaxf(a[3] * s3 + o3, 0.f));
                *(ushort4*)&h1[(size_t)n * 256 + c] = pk;
            }
        }
    }
}

// ---------------- P1: sum h1 rows per graph (h1 bf16, pair loads) ----------------
__global__ __launch_bounds__(256) void k_p1(const uint32* __restrict__ h2,
                                            const int* __restrict__ batch,
                                            float* __restrict__ P1,
                                            float* __restrict__ cnt, int N) {
    int t = threadIdx.x;
    int sub = t >> 7;
    int p = t & 127;
    int lo = blockIdx.x * 128 + sub * 64;
    if (lo >= N) return;
    int hi = min(lo + 64, N);
    float r0 = 0.f, r1 = 0.f;
    int count = 0;
    int curg = batch[lo];
    for (int n = lo; n < hi; n++) {
        int g = batch[n];
        if (g != curg) {
            atomicAdd(&P1[curg * 256 + 2 * p], r0);
            atomicAdd(&P1[curg * 256 + 2 * p + 1], r1);
            if (p == 0) atomicAdd(&cnt[curg], (float)count);
            r0 = r1 = 0.f; count = 0; curg = g;
        }
        uint32 u = h2[(size_t)n * 128 + p];
        r0 += bf_lo(u); r1 += bf_hi(u);
        count++;
    }
    atomicAdd(&P1[curg * 256 + 2 * p], r0);
    atomicAdd(&P1[curg * 256 + 2 * p + 1], r1);
    if (p == 0) atomicAdd(&cnt[curg], (float)count);
}

// ---------------- P2: CSR-slot-ordered weighted gather-sum of h1 (bf16) ----------------
__global__ __launch_bounds__(256) void k_p2(const uint32* __restrict__ h2,
                                            const int* __restrict__ col,
                                            const float* __restrict__ eW,
                                            const int* __restrict__ eG,
                                            float* __restrict__ P2, int E) {
    int t = threadIdx.x;
    int half = t >> 7;
    int p = t & 127;
    int per = (E + gridDim.x - 1) / gridDim.x;
    int b0 = blockIdx.x * per;
    int b1e = min(b0 + per, E);
    if (b0 >= b1e) return;
    int mid = b0 + ((b1e - b0) >> 1);
    int e0 = half ? mid : b0;
    int e1 = half ? b1e : mid;
    if (e0 >= e1) return;
    float r0 = 0.f, r1 = 0.f;
    int curg = eG[e0];
    int e = e0;
    while (e < e1) {
        if (e + 8 <= e1 && eG[e + 7] == curg) {
            int s0 = col[e + 0], s1 = col[e + 1], s2 = col[e + 2], s3 = col[e + 3];
            int s4 = col[e + 4], s5 = col[e + 5], s6 = col[e + 6], s7 = col[e + 7];
            float w0 = eW[e + 0], w1 = eW[e + 1], w2 = eW[e + 2], w3 = eW[e + 3];
            float w4 = eW[e + 4], w5 = eW[e + 5], w6 = eW[e + 6], w7 = eW[e + 7];
            uint32 u0 = h2[(size_t)s0 * 128 + p];
            uint32 u1 = h2[(size_t)s1 * 128 + p];
            uint32 u2 = h2[(size_t)s2 * 128 + p];
            uint32 u3 = h2[(size_t)s3 * 128 + p];
            uint32 u4 = h2[(size_t)s4 * 128 + p];
            uint32 u5 = h2[(size_t)s5 * 128 + p];
            uint32 u6 = h2[(size_t)s6 * 128 + p];
            uint32 u7 = h2[(size_t)s7 * 128 + p];
            r0 += ((bf_lo(u0) * w0 + bf_lo(u1) * w1) + (bf_lo(u2) * w2 + bf_lo(u3) * w3)) +
                  ((bf_lo(u4) * w4 + bf_lo(u5) * w5) + (bf_lo(u6) * w6 + bf_lo(u7) * w7));
            r1 += ((bf_hi(u0) * w0 + bf_hi(u1) * w1) + (bf_hi(u2) * w2 + bf_hi(u3) * w3)) +
                  ((bf_hi(u4) * w4 + bf_hi(u5) * w5) + (bf_hi(u6) * w6 + bf_hi(u7) * w7));
            e += 8;
        } else {
            int g = eG[e];
            if (g != curg) {
                atomicAdd(&P2[curg * 256 + 2 * p], r0);
                atomicAdd(&P2[curg * 256 + 2 * p + 1], r1);
                r0 = r1 = 0.f;
                curg = g;
            }
            uint32 u = h2[(size_t)col[e] * 128 + p];
            float w = eW[e];
            r0 += bf_lo(u) * w; r1 += bf_hi(u) * w;
            e++;
        }
    }
    atomicAdd(&P2[curg * 256 + 2 * p], r0);
    atomicAdd(&P2[curg * 256 + 2 * p + 1], r1);
}

// ---------------- classifier (fp32): one block per graph ----------------
__global__ __launch_bounds__(256) void k_classifier(
        const float* __restrict__ P1, const float* __restrict__ P2,
        const float* __restrict__ cnt,
        const float* __restrict__ W2a, const float* __restrict__ W2r,
        const float* __restrict__ b2,
        const float* __restrict__ Wc1, const float* __restrict__ bc1,
        const float* __restrict__ Wc2, const float* __restrict__ bc2,
        float* __restrict__ out) {
    __shared__ float p1s[256], p2s[256], g2[256], c1s[128], lg[2];
    int g = blockIdx.x, t = threadIdx.x;
    p1s[t] = P1[g * 256 + t];
    p2s[t] = P2[g * 256 + t];
    __syncthreads();
    float acc = 0.f;
    for (int k = 0; k < 256; k++)
        acc += p2s[k] * W2a[k * 256 + t] + p1s[k] * W2r[k * 256 + t];
    float c = cnt[g];
    float inv = 1.0f / fmaxf(c, 1.0f);
    g2[t] = (acc + c * b2[t]) * inv;
    __syncthreads();
    if (t < 128) {
        float a = bc1[t];
        for (int k = 0; k < 256; k++) a += g2[k] * Wc1[k * 128 + t];
        c1s[t] = fmaxf(a, 0.f);
    }
    __syncthreads();
    if (t < 2) {
        float a = bc2[t];
        for (int k = 0; k < 128; k++) a += c1s[k] * Wc2[k * 2 + t];
        lg[t] = a;
    }
    __syncthreads();
    if (t == 0) {
        float m = fmaxf(lg[0], lg[1]);
        float lse = m + logf(expf(lg[0] - m) + expf(lg[1] - m));
        out[g * 2 + 0] = lg[0] - lse;
        out[g * 2 + 1] = lg[1] - lse;
    }
}

extern "C" void kernel_launch(void* const* d_in, const int* in_sizes, int n_in,
                              void* d_out, int out_size, void* d_ws, size_t ws_size,
                              hipStream_t stream) {
    const float* x     = (const float*)d_in[0];
    const int*   edge  = (const int*)d_in[1];
    const int*   batch = (const int*)d_in[2];
    const float* W1a   = (const float*)d_in[3];
    const float* W1r   = (const float*)d_in[4];
    const float* b1    = (const float*)d_in[5];
    const float* gamma = (const float*)d_in[6];
    const float* beta  = (const float*)d_in[7];
    const float* mean  = (const float*)d_in[8];
    const float* var   = (const float*)d_in[9];
    const float* W2a   = (const float*)d_in[10];
    const float* W2r   = (const float*)d_in[11];
    const float* b2    = (const float*)d_in[12];
    const float* Wc1   = (const float*)d_in[13];
    const float* bc1   = (const float*)d_in[14];
    const float* Wc2   = (const float*)d_in[15];
    const float* bc2   = (const float*)d_in[16];
    float* out = (float*)d_out;

    const int N = N_NODES;
    const int E = in_sizes[1] / 2;
    const int* src = edge;
    const int* dst = edge + E;

    char* wsp = (char*)d_ws;
    auto alloc = [&](size_t bytes) {
        char* p = wsp;
        wsp += (bytes + 255) & ~(size_t)255;
        return p;
    };
    int*      deg    = (int*)alloc((size_t)N * 4);
    int*      pos    = (int*)alloc((size_t)N * 4);
    float*    P1     = (float*)alloc((size_t)N_GRAPHS * 256 * 4);
    float*    P2     = (float*)alloc((size_t)N_GRAPHS * 256 * 4);
    float*    cnt    = (float*)alloc(256 * 4);
    char*     zero_end = wsp;
    int*      rowptr = (int*)alloc((size_t)(N + 1) * 4);
    float*    invdeg = (float*)alloc((size_t)N * 4);
    int*      col    = (int*)alloc((size_t)E * 4);
    float*    eW     = (float*)alloc((size_t)E * 4);
    int*      eG     = (int*)alloc((size_t)E * 4);
    ushort16* xb     = (ushort16*)alloc((size_t)N * IN_C * 2);
    ushort16* aggb   = (ushort16*)alloc((size_t)N * IN_C * 2);
    ushort16* WThi   = (ushort16*)alloc((size_t)HID * HID * 2);
    ushort16* WTlo   = (ushort16*)alloc((size_t)HID * HID * 2);
    ushort16* h1     = (ushort16*)alloc((size_t)N * HID * 2);

    hipMemsetAsync(deg, 0, (size_t)(zero_end - (char*)deg), stream);

    k_count_deg<<<(E + 255) / 256, 256, 0, stream>>>(dst, deg, E);
    k_cvt_x<<<(N * IN_C / 4 + 255) / 256, 256, 0, stream>>>((const float4*)x, (ushort4*)xb,
                                                            N * IN_C / 4);
    k_prep_w<<<HID, HID, 0, stream>>>(W1r, W1a, WThi, WTlo);
    k_scan<<<1, 1024, 0, stream>>>(deg, rowptr, invdeg, N);
    k_fill_csr<<<(E + 255) / 256, 256, 0, stream>>>(src, dst, batch, invdeg, rowptr,
                                                    pos, col, eW, eG, E);
    k_agg1<<<(N + 3) / 4, 256, 0, stream>>>((const uint32*)xb, rowptr, col, invdeg,
                                            (uint32*)aggb, N);
    k_gemm1<<<(N + 63) / 64, 256, 0, stream>>>(xb, aggb, WThi, WTlo, b1, gamma, beta,
                                               mean, var, h1, N);
    k_p1<<<(N + 127) / 128, 256, 0, stream>>>((const uint32*)h1, batch, P1, cnt, N);
    k_p2<<<2048, 256, 0, stream>>>((const uint32*)h1, col, eW, eG, P2, E);
    k_classifier<<<N_GRAPHS, 256, 0, stream>>>(P1, P2, cnt, W2a, W2r, b2,
                                               Wc1, bc1, Wc2, bc2, out);
}

// Round 4
// 480.810 us; speedup vs baseline: 2.5412x; 1.4603x over previous
//
#include <hip/hip_runtime.h>
#include <math.h>

#define N_NODES 100000
#define IN_C 128
#define HID 256
#define N_GRAPHS 64
#define BN_EPS 1e-5f
#define SCAN_CH 512   // nodes per scan block; G = ceil(N/512) = 196 <= 256

typedef unsigned int   uint32;
typedef unsigned short ushort16;
typedef __attribute__((ext_vector_type(8))) short bf16x8;
typedef __attribute__((ext_vector_type(4))) float f32x4;

__device__ __forceinline__ float bf_lo(uint32 u) { return __builtin_bit_cast(float, u << 16); }
__device__ __forceinline__ float bf_hi(uint32 u) { return __builtin_bit_cast(float, u & 0xffff0000u); }
__device__ __forceinline__ ushort16 f2bf(float f) {   // round-to-nearest-even
    uint32 u = __builtin_bit_cast(uint32, f);
    return (ushort16)((u + 0x7fffu + ((u >> 16) & 1u)) >> 16);
}

// ---------------- degree count ----------------
__global__ void k_count_deg(const int* __restrict__ dst, int* __restrict__ deg, int E) {
    int e = blockIdx.x * blockDim.x + threadIdx.x;
    if (e < E) atomicAdd(&deg[dst[e]], 1);
}

// ---------------- x fp32 -> bf16 ----------------
__global__ void k_cvt_x(const float4* __restrict__ x4, ushort4* __restrict__ xb4, int n4) {
    int i = blockIdx.x * blockDim.x + threadIdx.x;
    if (i >= n4) return;
    float4 v = x4[i];
    ushort4 o;
    o.x = f2bf(v.x); o.y = f2bf(v.y); o.z = f2bf(v.z); o.w = f2bf(v.w);
    xb4[i] = o;
}

// ---------------- build WT hi/lo: WT[c][k] = Wcat[k][c], split-bf16 ----------------
__global__ void k_prep_w(const float* __restrict__ W1r, const float* __restrict__ W1a,
                         ushort16* __restrict__ WThi, ushort16* __restrict__ WTlo) {
    int c = blockIdx.x;
    int k = threadIdx.x;
    float v = (k < 128) ? W1r[(size_t)k * 256 + c] : W1a[(size_t)(k - 128) * 256 + c];
    ushort16 h = f2bf(v);
    float vh = __builtin_bit_cast(float, ((uint32)h) << 16);
    ushort16 l = f2bf(v - vh);
    WThi[c * 256 + k] = h;
    WTlo[c * 256 + k] = l;
}

// ---------------- 3-phase device-wide scan ----------------
// phase 1: per-block chunk sum
__global__ __launch_bounds__(256) void k_scan1(const int* __restrict__ deg,
                                               int* __restrict__ bsum, int N) {
    __shared__ int ws[4];
    int b = blockIdx.x;
    int base = b * SCAN_CH;
    int t = threadIdx.x;
    int v = 0;
    int i0 = base + t;
    int i1 = base + 256 + t;
    if (i0 < N) v = deg[i0];
    if (i1 < N && 256 + t < SCAN_CH) v += deg[i1];
#pragma unroll
    for (int off = 32; off; off >>= 1) v += __shfl_down(v, off);
    if ((t & 63) == 0) ws[t >> 6] = v;
    __syncthreads();
    if (t == 0) bsum[b] = ws[0] + ws[1] + ws[2] + ws[3];
}

// phase 2: exclusive scan of block sums (G <= 256), writes rowptr[N]=total
__global__ __launch_bounds__(256) void k_scan2(const int* __restrict__ bsum,
                                               int* __restrict__ boff,
                                               int* __restrict__ rowptr, int G, int N) {
    __shared__ int part[256];
    int t = threadIdx.x;
    int v = (t < G) ? bsum[t] : 0;
    part[t] = v;
    __syncthreads();
    for (int off = 1; off < 256; off <<= 1) {
        int u = (t >= off) ? part[t - off] : 0;
        __syncthreads();
        part[t] += u;
        __syncthreads();
    }
    if (t < G) boff[t] = part[t] - v;
    if (t == 255) rowptr[N] = part[255];
}

// phase 3: per-block exclusive scan -> rowptr, invdeg
__global__ __launch_bounds__(256) void k_scan3(const int* __restrict__ deg,
                                               const int* __restrict__ boff,
                                               int* __restrict__ rowptr,
                                               float* __restrict__ invdeg, int N) {
    __shared__ int ts[256];
    int b = blockIdx.x;
    int base = b * SCAN_CH;
    int t = threadIdx.x;
    int i0 = base + 2 * t, i1 = i0 + 1;
    int d0 = (i0 < N) ? deg[i0] : 0;
    int d1 = (i1 < N) ? deg[i1] : 0;
    int s = d0 + d1;
    ts[t] = s;
    __syncthreads();
    for (int off = 1; off < 256; off <<= 1) {
        int u = (t >= off) ? ts[t - off] : 0;
        __syncthreads();
        ts[t] += u;
        __syncthreads();
    }
    int run = boff[b] + ts[t] - s;
    if (i0 < N) { rowptr[i0] = run; invdeg[i0] = 1.0f / (float)max(d0, 1); run += d0; }
    if (i1 < N) { rowptr[i1] = run; invdeg[i1] = 1.0f / (float)max(d1, 1); }
}

// ---------------- fill CSR (slot-ordered eW/eG => eG non-decreasing) ----------------
__global__ void k_fill_csr(const int* __restrict__ src, const int* __restrict__ dst,
                           const int* __restrict__ batch, const float* __restrict__ invdeg,
                           const int* __restrict__ rowptr, int* __restrict__ pos,
                           int* __restrict__ col, float* __restrict__ eW,
                           int* __restrict__ eG, int E) {
    int e = blockIdx.x * blockDim.x + threadIdx.x;
    if (e >= E) return;
    int d = dst[e];
    int slot = rowptr[d] + atomicAdd(&pos[d], 1);
    col[slot] = src[e];
    eW[slot] = invdeg[d];
    eG[slot] = batch[d];
}

// ---------------- layer-1 aggregation (bf16 in/out): one wave per node ----------------
__global__ __launch_bounds__(256) void k_agg1(const uint32* __restrict__ xb2,
                                              const int* __restrict__ rowptr,
                                              const int* __restrict__ col,
                                              const float* __restrict__ invdeg,
                                              uint32* __restrict__ aggb2, int N) {
    int wave = (int)((blockIdx.x * blockDim.x + threadIdx.x) >> 6);
    int lane = threadIdx.x & 63;
    if (wave >= N) return;
    int lo = rowptr[wave], hi = rowptr[wave + 1];
    float ax = 0.f, ay = 0.f;
    int j = lo;
    for (; j + 4 <= hi; j += 4) {
        int s0 = col[j], s1 = col[j + 1], s2 = col[j + 2], s3 = col[j + 3];
        uint32 u0 = xb2[(size_t)s0 * 64 + lane];
        uint32 u1 = xb2[(size_t)s1 * 64 + lane];
        uint32 u2 = xb2[(size_t)s2 * 64 + lane];
        uint32 u3 = xb2[(size_t)s3 * 64 + lane];
        ax += (bf_lo(u0) + bf_lo(u1)) + (bf_lo(u2) + bf_lo(u3));
        ay += (bf_hi(u0) + bf_hi(u1)) + (bf_hi(u2) + bf_hi(u3));
    }
    for (; j < hi; j++) {
        uint32 u = xb2[(size_t)col[j] * 64 + lane];
        ax += bf_lo(u); ay += bf_hi(u);
    }
    float w = invdeg[wave];
    uint32 p = (uint32)f2bf(ax * w) | (((uint32)f2bf(ay * w)) << 16);
    aggb2[(size_t)wave * 64 + lane] = p;
}

// ---------------- fused MFMA GEMM1 + bias + BN(eval) + ReLU -> h1 bf16 ----------------
__global__ __launch_bounds__(256) void k_gemm1(
        const ushort16* __restrict__ xb, const ushort16* __restrict__ aggb,
        const ushort16* __restrict__ WThi, const ushort16* __restrict__ WTlo,
        const float* __restrict__ b1, const float* __restrict__ gamma,
        const float* __restrict__ beta, const float* __restrict__ mean,
        const float* __restrict__ var, ushort16* __restrict__ h1, int N) {
    int n0 = blockIdx.x * 64;
    int w = threadIdx.x >> 6;
    int l = threadIdx.x & 63;
    int l15 = l & 15;
    int lg = l >> 4;
    int ocb = w * 64;

    f32x4 acc[4][4];
#pragma unroll
    for (int i = 0; i < 4; i++)
#pragma unroll
        for (int j = 0; j < 4; j++) acc[i][j] = (f32x4)0.f;

    int nidx[4];
#pragma unroll
    for (int nt = 0; nt < 4; nt++) nidx[nt] = min(n0 + nt * 16 + l15, N - 1);

    const ushort16* wrh[4];
    const ushort16* wrl[4];
#pragma unroll
    for (int ot = 0; ot < 4; ot++) {
        size_t off = (size_t)(ocb + ot * 16 + l15) * 256 + lg * 8;
        wrh[ot] = WThi + off;
        wrl[ot] = WTlo + off;
    }

#pragma unroll
    for (int ks = 0; ks < 4; ks++) {
        int k0 = ks * 32;
        bf16x8 wh[4], wl[4], bx[4];
#pragma unroll
        for (int ot = 0; ot < 4; ot++) {
            wh[ot] = *(const bf16x8*)(wrh[ot] + k0);
            wl[ot] = *(const bf16x8*)(wrl[ot] + k0);
        }
#pragma unroll
        for (int nt = 0; nt < 4; nt++)
            bx[nt] = *(const bf16x8*)(xb + (size_t)nidx[nt] * 128 + k0 + lg * 8);
#pragma unroll
        for (int ot = 0; ot < 4; ot++)
#pragma unroll
            for (int nt = 0; nt < 4; nt++) {
                acc[ot][nt] = __builtin_amdgcn_mfma_f32_16x16x32_bf16(wh[ot], bx[nt], acc[ot][nt], 0, 0, 0);
                acc[ot][nt] = __builtin_amdgcn_mfma_f32_16x16x32_bf16(wl[ot], bx[nt], acc[ot][nt], 0, 0, 0);
            }
    }
#pragma unroll
    for (int ks = 0; ks < 4; ks++) {
        int k0 = 128 + ks * 32;
        bf16x8 wh[4], wl[4], bx[4];
#pragma unroll
        for (int ot = 0; ot < 4; ot++) {
            wh[ot] = *(const bf16x8*)(wrh[ot] + k0);
            wl[ot] = *(const bf16x8*)(wrl[ot] + k0);
        }
#pragma unroll
        for (int nt = 0; nt < 4; nt++)
            bx[nt] = *(const bf16x8*)(aggb + (size_t)nidx[nt] * 128 + ks * 32 + lg * 8);
#pragma unroll
        for (int ot = 0; ot < 4; ot++)
#pragma unroll
            for (int nt = 0; nt < 4; nt++) {
                acc[ot][nt] = __builtin_amdgcn_mfma_f32_16x16x32_bf16(wh[ot], bx[nt], acc[ot][nt], 0, 0, 0);
                acc[ot][nt] = __builtin_amdgcn_mfma_f32_16x16x32_bf16(wl[ot], bx[nt], acc[ot][nt], 0, 0, 0);
            }
    }

#pragma unroll
    for (int ot = 0; ot < 4; ot++) {
        int c = ocb + ot * 16 + lg * 4;
        float4 gm = *(const float4*)&gamma[c];
        float4 bt = *(const float4*)&beta[c];
        float4 mn = *(const float4*)&mean[c];
        float4 vr = *(const float4*)&var[c];
        float4 bb = *(const float4*)&b1[c];
        float s0 = gm.x * rsqrtf(vr.x + BN_EPS);
        float s1 = gm.y * rsqrtf(vr.y + BN_EPS);
        float s2 = gm.z * rsqrtf(vr.z + BN_EPS);
        float s3 = gm.w * rsqrtf(vr.w + BN_EPS);
        float o0 = bt.x + (bb.x - mn.x) * s0;
        float o1 = bt.y + (bb.y - mn.y) * s1;
        float o2 = bt.z + (bb.z - mn.z) * s2;
        float o3 = bt.w + (bb.w - mn.w) * s3;
#pragma unroll
        for (int nt = 0; nt < 4; nt++) {
            int n = n0 + nt * 16 + l15;
            if (n < N) {
                f32x4 a = acc[ot][nt];
                ushort4 pk;
                pk.x = f2bf(fmaxf(a[0] * s0 + o0, 0.f));
                pk.y = f2bf(fmaxf(a[1] * s1 + o1, 0.f));
                pk.z = f2bf(fmaxf(a[2] * s2 + o2, 0.f));
                pk.w = f2bf(fmaxf(a[3] * s3 + o3, 0.f));
                *(ushort4*)&h1[(size_t)n * 256 + c] = pk;
            }
        }
    }
}

// ---------------- P1: sum h1 rows per graph (h1 bf16, pair loads) ----------------
__global__ __launch_bounds__(256) void k_p1(const uint32* __restrict__ h2,
                                            const int* __restrict__ batch,
                                            float* __restrict__ P1,
                                            float* __restrict__ cnt, int N) {
    int t = threadIdx.x;
    int sub = t >> 7;
    int p = t & 127;
    int lo = blockIdx.x * 128 + sub * 64;
    if (lo >= N) return;
    int hi = min(lo + 64, N);
    float r0 = 0.f, r1 = 0.f;
    int count = 0;
    int curg = batch[lo];
    for (int n = lo; n < hi; n++) {
        int g = batch[n];
        if (g != curg) {
            atomicAdd(&P1[curg * 256 + 2 * p], r0);
            atomicAdd(&P1[curg * 256 + 2 * p + 1], r1);
            if (p == 0) atomicAdd(&cnt[curg], (float)count);
            r0 = r1 = 0.f; count = 0; curg = g;
        }
        uint32 u = h2[(size_t)n * 128 + p];
        r0 += bf_lo(u); r1 += bf_hi(u);
        count++;
    }
    atomicAdd(&P1[curg * 256 + 2 * p], r0);
    atomicAdd(&P1[curg * 256 + 2 * p + 1], r1);
    if (p == 0) atomicAdd(&cnt[curg], (float)count);
}

// ---------------- P2: CSR-slot-ordered weighted gather-sum of h1 (bf16) ----------------
__global__ __launch_bounds__(256) void k_p2(const uint32* __restrict__ h2,
                                            const int* __restrict__ col,
                                            const float* __restrict__ eW,
                                            const int* __restrict__ eG,
                                            float* __restrict__ P2, int E) {
    int t = threadIdx.x;
    int half = t >> 7;
    int p = t & 127;
    int per = (E + gridDim.x - 1) / gridDim.x;
    int b0 = blockIdx.x * per;
    int b1e = min(b0 + per, E);
    if (b0 >= b1e) return;
    int mid = b0 + ((b1e - b0) >> 1);
    int e0 = half ? mid : b0;
    int e1 = half ? b1e : mid;
    if (e0 >= e1) return;
    float r0 = 0.f, r1 = 0.f;
    int curg = eG[e0];
    int e = e0;
    while (e < e1) {
        if (e + 8 <= e1 && eG[e + 7] == curg) {
            int s0 = col[e + 0], s1 = col[e + 1], s2 = col[e + 2], s3 = col[e + 3];
            int s4 = col[e + 4], s5 = col[e + 5], s6 = col[e + 6], s7 = col[e + 7];
            float w0 = eW[e + 0], w1 = eW[e + 1], w2 = eW[e + 2], w3 = eW[e + 3];
            float w4 = eW[e + 4], w5 = eW[e + 5], w6 = eW[e + 6], w7 = eW[e + 7];
            uint32 u0 = h2[(size_t)s0 * 128 + p];
            uint32 u1 = h2[(size_t)s1 * 128 + p];
            uint32 u2 = h2[(size_t)s2 * 128 + p];
            uint32 u3 = h2[(size_t)s3 * 128 + p];
            uint32 u4 = h2[(size_t)s4 * 128 + p];
            uint32 u5 = h2[(size_t)s5 * 128 + p];
            uint32 u6 = h2[(size_t)s6 * 128 + p];
            uint32 u7 = h2[(size_t)s7 * 128 + p];
            r0 += ((bf_lo(u0) * w0 + bf_lo(u1) * w1) + (bf_lo(u2) * w2 + bf_lo(u3) * w3)) +
                  ((bf_lo(u4) * w4 + bf_lo(u5) * w5) + (bf_lo(u6) * w6 + bf_lo(u7) * w7));
            r1 += ((bf_hi(u0) * w0 + bf_hi(u1) * w1) + (bf_hi(u2) * w2 + bf_hi(u3) * w3)) +
                  ((bf_hi(u4) * w4 + bf_hi(u5) * w5) + (bf_hi(u6) * w6 + bf_hi(u7) * w7));
            e += 8;
        } else {
            int g = eG[e];
            if (g != curg) {
                atomicAdd(&P2[curg * 256 + 2 * p], r0);
                atomicAdd(&P2[curg * 256 + 2 * p + 1], r1);
                r0 = r1 = 0.f;
                curg = g;
            }
            uint32 u = h2[(size_t)col[e] * 128 + p];
            float w = eW[e];
            r0 += bf_lo(u) * w; r1 += bf_hi(u) * w;
            e++;
        }
    }
    atomicAdd(&P2[curg * 256 + 2 * p], r0);
    atomicAdd(&P2[curg * 256 + 2 * p + 1], r1);
}

// ---------------- classifier (fp32): one block per graph ----------------
__global__ __launch_bounds__(256) void k_classifier(
        const float* __restrict__ P1, const float* __restrict__ P2,
        const float* __restrict__ cnt,
        const float* __restrict__ W2a, const float* __restrict__ W2r,
        const float* __restrict__ b2,
        const float* __restrict__ Wc1, const float* __restrict__ bc1,
        const float* __restrict__ Wc2, const float* __restrict__ bc2,
        float* __restrict__ out) {
    __shared__ float p1s[256], p2s[256], g2[256], c1s[128], lg[2];
    int g = blockIdx.x, t = threadIdx.x;
    p1s[t] = P1[g * 256 + t];
    p2s[t] = P2[g * 256 + t];
    __syncthreads();
    float acc = 0.f;
    for (int k = 0; k < 256; k++)
        acc += p2s[k] * W2a[k * 256 + t] + p1s[k] * W2r[k * 256 + t];
    float c = cnt[g];
    float inv = 1.0f / fmaxf(c, 1.0f);
    g2[t] = (acc + c * b2[t]) * inv;
    __syncthreads();
    if (t < 128) {
        float a = bc1[t];
        for (int k = 0; k < 256; k++) a += g2[k] * Wc1[k * 128 + t];
        c1s[t] = fmaxf(a, 0.f);
    }
    __syncthreads();
    if (t < 2) {
        float a = bc2[t];
        for (int k = 0; k < 128; k++) a += c1s[k] * Wc2[k * 2 + t];
        lg[t] = a;
    }
    __syncthreads();
    if (t == 0) {
        float m = fmaxf(lg[0], lg[1]);
        float lse = m + logf(expf(lg[0] - m) + expf(lg[1] - m));
        out[g * 2 + 0] = lg[0] - lse;
        out[g * 2 + 1] = lg[1] - lse;
    }
}

extern "C" void kernel_launch(void* const* d_in, const int* in_sizes, int n_in,
                              void* d_out, int out_size, void* d_ws, size_t ws_size,
                              hipStream_t stream) {
    const float* x     = (const float*)d_in[0];
    const int*   edge  = (const int*)d_in[1];
    const int*   batch = (const int*)d_in[2];
    const float* W1a   = (const float*)d_in[3];
    const float* W1r   = (const float*)d_in[4];
    const float* b1    = (const float*)d_in[5];
    const float* gamma = (const float*)d_in[6];
    const float* beta  = (const float*)d_in[7];
    const float* mean  = (const float*)d_in[8];
    const float* var   = (const float*)d_in[9];
    const float* W2a   = (const float*)d_in[10];
    const float* W2r   = (const float*)d_in[11];
    const float* b2    = (const float*)d_in[12];
    const float* Wc1   = (const float*)d_in[13];
    const float* bc1   = (const float*)d_in[14];
    const float* Wc2   = (const float*)d_in[15];
    const float* bc2   = (const float*)d_in[16];
    float* out = (float*)d_out;

    const int N = N_NODES;
    const int E = in_sizes[1] / 2;
    const int* src = edge;
    const int* dst = edge + E;
    const int G = (N + SCAN_CH - 1) / SCAN_CH;

    char* wsp = (char*)d_ws;
    auto alloc = [&](size_t bytes) {
        char* p = wsp;
        wsp += (bytes + 255) & ~(size_t)255;
        return p;
    };
    int*      deg    = (int*)alloc((size_t)N * 4);
    int*      pos    = (int*)alloc((size_t)N * 4);
    float*    P1     = (float*)alloc((size_t)N_GRAPHS * 256 * 4);
    float*    P2     = (float*)alloc((size_t)N_GRAPHS * 256 * 4);
    float*    cnt    = (float*)alloc(256 * 4);
    char*     zero_end = wsp;
    int*      rowptr = (int*)alloc((size_t)(N + 1) * 4);
    float*    invdeg = (float*)alloc((size_t)N * 4);
    int*      bsum   = (int*)alloc(256 * 4);
    int*      boff   = (int*)alloc(256 * 4);
    int*      col    = (int*)alloc((size_t)E * 4);
    float*    eW     = (float*)alloc((size_t)E * 4);
    int*      eG     = (int*)alloc((size_t)E * 4);
    ushort16* xb     = (ushort16*)alloc((size_t)N * IN_C * 2);
    ushort16* aggb   = (ushort16*)alloc((size_t)N * IN_C * 2);
    ushort16* WThi   = (ushort16*)alloc((size_t)HID * HID * 2);
    ushort16* WTlo   = (ushort16*)alloc((size_t)HID * HID * 2);
    ushort16* h1     = (ushort16*)alloc((size_t)N * HID * 2);

    hipMemsetAsync(deg, 0, (size_t)(zero_end - (char*)deg), stream);

    k_count_deg<<<(E + 255) / 256, 256, 0, stream>>>(dst, deg, E);
    k_cvt_x<<<(N * IN_C / 4 + 255) / 256, 256, 0, stream>>>((const float4*)x, (ushort4*)xb,
                                                            N * IN_C / 4);
    k_prep_w<<<HID, HID, 0, stream>>>(W1r, W1a, WThi, WTlo);
    k_scan1<<<G, 256, 0, stream>>>(deg, bsum, N);
    k_scan2<<<1, 256, 0, stream>>>(bsum, boff, rowptr, G, N);
    k_scan3<<<G, 256, 0, stream>>>(deg, boff, rowptr, invdeg, N);
    k_fill_csr<<<(E + 255) / 256, 256, 0, stream>>>(src, dst, batch, invdeg, rowptr,
                                                    pos, col, eW, eG, E);
    k_agg1<<<(N + 3) / 4, 256, 0, stream>>>((const uint32*)xb, rowptr, col, invdeg,
                                            (uint32*)aggb, N);
    k_gemm1<<<(N + 63) / 64, 256, 0, stream>>>(xb, aggb, WThi, WTlo, b1, gamma, beta,
                                               mean, var, h1, N);
    k_p1<<<(N + 127) / 128, 256, 0, stream>>>((const uint32*)h1, batch, P1, cnt, N);
    k_p2<<<2048, 256, 0, stream>>>((const uint32*)h1, col, eW, eG, P2, E);
    k_classifier<<<N_GRAPHS, 256, 0, stream>>>(P1, P2, cnt, W2a, W2r, b2,
                                               Wc1, bc1, Wc2, bc2, out);
}